// Round 4
// baseline (39290.707 us; speedup 1.0000x reference)
//
#include <hip/hip_runtime.h>
#include <hip/hip_bf16.h>

// Bidirectional 2-layer LSTM, T=1024 B=64 H=512. R4: INPUTS/OUTPUT ARE FP32
// (reference is jnp.float32; R1-R3 read fp32 memory as bf16 -> low mantissa
// half-words decode as NaN-pattern bf16 ~0.4% of the time -> NaN everywhere.
// That was the NaN source; buffers/sync were fine.)
// Compute stays bf16 MFMA (threshold 2.3e-2 accommodates it):
//  - weights converted fp32->bf16 once during LDS staging (64 KB static/WG)
//  - x A-fragments converted fp32->bf16 in-loop (L0 stages only)
//  - h recurrence kept bf16 in static __device__ rings (L0 ring feeds L1's x;
//    L1 has its own ring for its h recurrence, and also writes fp32 h to out)
//  - bias added in fp32 accumulator domain; hidden/cell stored fp32.
// Persistent kernel: 256 WGs = 4 stages (L0F,L0B,L1F,L1B) x 64 WGs; each WG
// owns 8 h-cols (32 gate cols x K=1024 bf16 = 64 KB LDS, XOR-swizzled).
// Per-stage monotone atomic barriers; L1 elastically chases L0 via W=16 ring.

typedef __hip_bfloat16 bf16;
typedef short bf16x8 __attribute__((ext_vector_type(8)));   // 8 bf16 = 4 VGPRs
typedef float f32x4 __attribute__((ext_vector_type(4)));

constexpr int T = 1024, B = 64, H = 512, G4 = 2048;
constexpr int W = 16;         // ring slots per direction
constexpr int NW = 64;        // WGs per stage
constexpr size_t OUT_ELEMS = (size_t)T * B * 1024;          // 67,108,864
constexpr size_t HID_OFF   = OUT_ELEMS;                     // hidden [4,64,512]
constexpr size_t CELL_OFF  = OUT_ELEMS + (size_t)4 * B * H; // cell   [4,64,512]

__device__ unsigned g_ctrs[8];           // [0..3] stage barriers
__device__ bf16 g_ring [2 * W * B * H];  // L0 h rings (F,B) - 2 MB
__device__ bf16 g_ring2[2 * W * B * H];  // L1 h rings (F,B) - 2 MB

__global__ void init_ctrs() { if (threadIdx.x < 8) g_ctrs[threadIdx.x] = 0; }

__device__ __forceinline__ bf16x8 cvt8(const float* p) {
  const float4 u = *(const float4*)p;
  const float4 v = *(const float4*)(p + 4);
  union { bf16 h[8]; bf16x8 r; } o;
  o.h[0] = __float2bfloat16(u.x); o.h[1] = __float2bfloat16(u.y);
  o.h[2] = __float2bfloat16(u.z); o.h[3] = __float2bfloat16(u.w);
  o.h[4] = __float2bfloat16(v.x); o.h[5] = __float2bfloat16(v.y);
  o.h[6] = __float2bfloat16(v.z); o.h[7] = __float2bfloat16(v.w);
  return o.r;
}

__global__ void __launch_bounds__(256, 1)
lstm_bidir(const float* __restrict__ x,
           const float* Wxf, const float* bxf, const float* Whf, const float* bhf,
           const float* Wxb, const float* bxb, const float* Whb, const float* bhb,
           float* out)
{
  __shared__ bf16 Wl[32 * 1024];   // 64 KB: 32 gate-col rows x K=1024 (swizzled)

  const int tid   = threadIdx.x;
  const int bid   = blockIdx.x;
  const int stage = bid & 3;       // L0F,L0B,L1F,L1B
  const int wg    = bid >> 2;      // 0..63
  const int dir   = stage & 1;
  const int layer = stage >> 1;
  const int c0    = wg * 8;        // h-col base owned by this WG

  const float* Wx = dir ? Wxb : Wxf;
  const float* Wh = dir ? Whb : Whf;
  const float* bx = dir ? bxb : bxf;
  const float* bh = dir ? bhb : bhf;
  bf16* ring  = g_ring  + (size_t)dir * W * B * H;  // L0 h (also L1's x source)
  bf16* ring2 = g_ring2 + (size_t)dir * W * B * H;  // L1 h recurrence

  // ---- stage weight slice into LDS (fp32 -> bf16); row n = j*4+g
  // 16B block kb stored at physical block kb ^ (n&7)  (bank de-conflict)
  for (int c = tid; c < 32 * 128; c += 256) {
    const int n  = c >> 7;               // 0..31
    const int kb = c & 127;              // 16B-bf16 block in K
    const int ke = kb * 8;               // elem offset 0..1016
    const int j = n >> 2, g = n & 3;
    const size_t row = (size_t)layer * G4 + (size_t)g * H + (c0 + j);
    const float* src = (ke < H) ? (Wx + row * H + ke) : (Wh + row * H + (ke - H));
    bf16x8 wv = cvt8(src);
    *(bf16x8*)(Wl + n * 1024 + ((kb ^ (n & 7)) * 8)) = wv;
  }

  const int lane = tid & 63, wi = tid >> 6;   // 4 waves
  const int quad = lane >> 4, mr = lane & 15;
  const int g2 = wi & 1;          // wave's 16-col group
  const int mh = wi >> 1;         // wave's 32-row half
  const int nb = g2 * 16 + mr;    // gate col within WG (0..31)
  const int j  = nb >> 2, gg = nb & 3;        // h-col within WG, gate id
  const int sw = nb & 7;          // swizzle key for this lane's B row

  const size_t brow = (size_t)layer * G4 + (size_t)gg * H + (c0 + j);
  const float bias = bx[brow] + bh[brow];     // fp32

  __syncthreads();  // weights ready (intra-WG)

  float cst[2][4] = {};           // c-state rows mh*32+m*16+quad*4+rr, col j
  unsigned nrounds = 0;
  unsigned* myctr   = g_ctrs + stage;
  unsigned* prodctr = g_ctrs + dir;       // L1F<-ctr0, L1B<-ctr1
  unsigned* consctr = g_ctrs + 2 + dir;   // L0F back-pressure on ctr2, L0B ctr3

  const int r0 = (stage < 2) ? 0 : 1;
  for (int r = r0; r < r0 + T; ++r) {
    int t;
    if (stage == 0)      t = r;
    else if (stage == 1) t = (T - 1) - r;
    else if (stage == 2) t = r - 1;
    else                 t = T - r;

    const bool first = dir ? (t == T - 1) : (t == 0);
    const bool last  = dir ? (t == 0) : (t == T - 1);

    const float* xf = nullptr;      // L0: fp32 x
    const bf16 *xsb = nullptr;      // L1: bf16 x (= L0 ring)
    const bf16 *hsrc; bf16* hdst_bf; float* hdst_f32 = nullptr;
    if (stage < 2) {
      xf      = x    + (size_t)t * B * H;
      hsrc    = ring + (size_t)((r - 1) & (W - 1)) * B * H;
      hdst_bf = ring + (size_t)(r & (W - 1)) * B * H;
      if (r >= W) {  // consumer must have finished round r-W+1 (read slot r%W)
        const unsigned need = (unsigned)NW * (unsigned)(r - W + 1);
        if (tid == 0) {
          while (__hip_atomic_load(consctr, __ATOMIC_ACQUIRE, __HIP_MEMORY_SCOPE_AGENT) < need)
            __builtin_amdgcn_s_sleep(1);
        }
        __syncthreads();
      }
    } else {
      xsb      = ring  + (size_t)((r - 1) & (W - 1)) * B * H;  // L0's h for step t
      hsrc     = ring2 + (size_t)((r - 1) & (W - 1)) * B * H;  // own h_{t-1}
      hdst_bf  = ring2 + (size_t)(r & (W - 1)) * B * H;
      hdst_f32 = out + (size_t)t * B * 1024 + (size_t)dir * H;
      const unsigned need = (unsigned)NW * (unsigned)r;        // L0 done round r-1
      if (tid == 0) {
        while (__hip_atomic_load(prodctr, __ATOMIC_ACQUIRE, __HIP_MEMORY_SCOPE_AGENT) < need)
          __builtin_amdgcn_s_sleep(1);
        __threadfence();  // acquire before ring read
      }
      __syncthreads();
    }

    // ---- GEMM: C[64,32] = [x_t ; h_{t-1}] (K=1024) @ Wslice, fp32 accum
    f32x4 acc0 = {0.f, 0.f, 0.f, 0.f};
    f32x4 acc1 = {0.f, 0.f, 0.f, 0.f};
    const int arow = mh * 32 + mr;

    if (stage < 2) {
      #pragma unroll
      for (int kk = 0; kk < 16; ++kk) {   // x part (fp32 -> bf16): K 0..511
        const int blk = kk * 4 + quad;
        bf16x8 bfr = *(const bf16x8*)(Wl + nb * 1024 + ((blk ^ sw) * 8));
        const float* ap = xf + (size_t)arow * H + blk * 8;
        bf16x8 a0 = cvt8(ap);
        bf16x8 a1 = cvt8(ap + (size_t)16 * H);
        acc0 = __builtin_amdgcn_mfma_f32_16x16x32_bf16(a0, bfr, acc0, 0, 0, 0);
        acc1 = __builtin_amdgcn_mfma_f32_16x16x32_bf16(a1, bfr, acc1, 0, 0, 0);
      }
    } else {
      #pragma unroll
      for (int kk = 0; kk < 16; ++kk) {   // x part (bf16 ring): K 0..511
        const int blk = kk * 4 + quad;
        bf16x8 bfr = *(const bf16x8*)(Wl + nb * 1024 + ((blk ^ sw) * 8));
        const bf16* ap = xsb + (size_t)arow * H + blk * 8;
        bf16x8 a0 = *(const bf16x8*)(ap);
        bf16x8 a1 = *(const bf16x8*)(ap + (size_t)16 * H);
        acc0 = __builtin_amdgcn_mfma_f32_16x16x32_bf16(a0, bfr, acc0, 0, 0, 0);
        acc1 = __builtin_amdgcn_mfma_f32_16x16x32_bf16(a1, bfr, acc1, 0, 0, 0);
      }
    }
    if (!first) {
      #pragma unroll
      for (int kk = 0; kk < 16; ++kk) {   // h part (bf16): K 512..1023
        const int blk = 64 + kk * 4 + quad;
        bf16x8 bfr = *(const bf16x8*)(Wl + nb * 1024 + ((blk ^ sw) * 8));
        const bf16* ap = hsrc + (size_t)arow * H + (kk * 4 + quad) * 8;
        bf16x8 a0 = *(const bf16x8*)(ap);
        bf16x8 a1 = *(const bf16x8*)(ap + (size_t)16 * H);
        acc0 = __builtin_amdgcn_mfma_f32_16x16x32_bf16(a0, bfr, acc0, 0, 0, 0);
        acc1 = __builtin_amdgcn_mfma_f32_16x16x32_bf16(a1, bfr, acc1, 0, 0, 0);
      }
    }

    // ---- gates: lane holds gate gg of (row, col j); partners in lanes ^1^2^3
    #pragma unroll
    for (int m = 0; m < 2; ++m) {
      const f32x4 av = m ? acc1 : acc0;
      #pragma unroll
      for (int rr = 0; rr < 4; ++rr) {
        const float v  = av[rr] + bias;
        const float v1 = __shfl_xor(v, 1);
        const float v2 = __shfl_xor(v, 2);
        const float v3 = __shfl_xor(v, 3);
        float gi, gf, gc, go;
        if (gg == 0)      { gi = v;  gf = v1; gc = v2; go = v3; }
        else if (gg == 1) { gi = v1; gf = v;  gc = v3; go = v2; }
        else if (gg == 2) { gi = v2; gf = v3; gc = v;  go = v1; }
        else              { gi = v3; gf = v2; gc = v1; go = v;  }
        const float si = 1.f / (1.f + __expf(-gi));
        const float sf = 1.f / (1.f + __expf(-gf));
        const float so = 1.f / (1.f + __expf(-go));
        const float tc = 1.f - 2.f / (1.f + __expf(2.f * gc));   // tanh, sat-safe
        const float c2 = sf * cst[m][rr] + si * tc;
        cst[m][rr] = c2;
        const float th = 1.f - 2.f / (1.f + __expf(2.f * c2));
        const float hv = so * th;
        if (gg == 0) {
          const int b = mh * 32 + m * 16 + quad * 4 + rr;
          hdst_bf[(size_t)b * H + (c0 + j)] = (bf16)hv;
          if (stage >= 2) hdst_f32[(size_t)b * 1024 + (c0 + j)] = hv;
          if (last) {
            const size_t p = (size_t)(dir * 2 + layer) * (B * H) + (size_t)b * H + (c0 + j);
            out[HID_OFF + p]  = hv;
            out[CELL_OFF + p] = c2;
          }
        }
      }
    }

    // ---- per-stage barrier: release h writes, arrive, wait NW arrivals, acquire
    __syncthreads();
    ++nrounds;
    if (tid == 0) {
      __threadfence();  // release: drain this WG's h stores device-wide
      __hip_atomic_fetch_add(myctr, 1u, __ATOMIC_RELEASE, __HIP_MEMORY_SCOPE_AGENT);
      const unsigned tgt = (unsigned)NW * nrounds;
      while (__hip_atomic_load(myctr, __ATOMIC_ACQUIRE, __HIP_MEMORY_SCOPE_AGENT) < tgt)
        __builtin_amdgcn_s_sleep(1);
      __threadfence();  // acquire: siblings' h visible next round
    }
    __syncthreads();
  }
}

extern "C" void kernel_launch(void* const* d_in, const int* in_sizes, int n_in,
                              void* d_out, int out_size, void* d_ws, size_t ws_size,
                              hipStream_t stream) {
  const float* x   = (const float*)d_in[0];
  const float* Wxf = (const float*)d_in[1];
  const float* bxf = (const float*)d_in[2];
  const float* Whf = (const float*)d_in[3];
  const float* bhf = (const float*)d_in[4];
  const float* Wxb = (const float*)d_in[5];
  const float* bxb = (const float*)d_in[6];
  const float* Whb = (const float*)d_in[7];
  const float* bhb = (const float*)d_in[8];
  float* out = (float*)d_out;

  hipLaunchKernelGGL(init_ctrs, dim3(1), dim3(64), 0, stream);
  hipLaunchKernelGGL(lstm_bidir, dim3(256), dim3(256), 0, stream,
                     x, Wxf, bxf, Whf, bhf, Wxb, bxb, Whb, bhb, out);
}